// Round 15
// baseline (265.682 us; speedup 1.0000x reference)
//
#include <hip/hip_runtime.h>
#include <stdint.h>

#define KTOT 4507
#define POSTN 1000
#define ATOT 159882
#define NIMG 4
#define CAND_CAP 4096
#define SLOTCAP 5000  // (kept for ckey/cslot layout: koff spacing = lvl*1000)
#define BPI 22        // hist/gather blocks per image: 15+4+1+1+1

// ---------- helpers ----------

__device__ inline unsigned fmono(float f) {
    unsigned u = __float_as_uint(f);
    return (u & 0x80000000u) ? ~u : (u | 0x80000000u);
}
__device__ inline float fmono_inv(unsigned u) {
    unsigned b = (u & 0x80000000u) ? (u ^ 0x80000000u) : ~u;
    return __uint_as_float(b);
}

__device__ inline unsigned long long shfl_u64(unsigned long long v, int src) {
    int lo = __shfl((int)(unsigned)(v & 0xFFFFFFFFULL), src);
    int hi = __shfl((int)(unsigned)(v >> 32), src);
    return ((unsigned long long)(unsigned)hi << 32) | (unsigned)lo;
}

// exclusive prefix over a 1024-thread block; warpSums = LDS int[>=16]; call uniformly.
__device__ inline int blockExclScan(int v, int* warpSums) {
    int tid = threadIdx.x;
    int lane = tid & 63, wid = tid >> 6;
    int x = v;
#pragma unroll
    for (int d = 1; d < 64; d <<= 1) {
        int y = __shfl_up(x, d);
        if (lane >= d) x += y;
    }
    if (lane == 63) warpSums[wid] = x;
    __syncthreads();
    if (wid == 0) {
        int s = (lane < 16) ? warpSums[lane] : 0;
#pragma unroll
        for (int d = 1; d < 16; d <<= 1) {
            int y = __shfl_up(s, d);
            if (lane >= d) s += y;
        }
        if (lane < 16) warpSums[lane] = s;
    }
    __syncthreads();
    int wpre = (wid == 0) ? 0 : warpSums[wid - 1];
    return wpre + (x - v);
}

__device__ __constant__ int c_lvlOff[5] = {0, 120000, 150000, 157500, 159375};
__device__ __constant__ int c_lvlN[5]   = {120000, 30000, 7500, 1875, 507};
__device__ __constant__ int c_slsz[5]   = {8000, 7500, 7500, 1875, 507};
__device__ __constant__ int c_blvl[BPI] = {0,0,0,0,0,0,0,0,0,0,0,0,0,0,0, 1,1,1,1, 2, 3, 4};
__device__ __constant__ int c_bsl[BPI]  = {0,1,2,3,4,5,6,7,8,9,10,11,12,13,14, 0,1,2,3, 0, 0, 0};
__device__ __constant__ int c_bstart[5] = {0, 15, 19, 20, 21};
__device__ __constant__ int c_bcnt[5]   = {15, 4, 1, 1, 1};

// ---------- stage A1: sliced histogram -> PRIVATE per-segment hist (no atomics) ----------

__global__ __launch_bounds__(1024) void hist_kernel(const float* __restrict__ obj,
                                                    unsigned* __restrict__ ghist) {
    __shared__ unsigned hist[4096];
    int img = blockIdx.x / BPI, b = blockIdx.x % BPI;
    int lvl = c_blvl[b], sl = c_bsl[b];
    int n = c_lvlN[lvl];
    int s0 = sl * c_slsz[lvl];
    int send = min(s0 + c_slsz[lvl], n);
    const float* src = obj + (size_t)img * ATOT + c_lvlOff[lvl];
    int tid = threadIdx.x;

    for (int i = tid; i < 4096; i += 1024) hist[i] = 0u;
    __syncthreads();

    int base = s0 + tid, last = send - 1;
    float v0 = src[min(base,        last)];
    float v1 = src[min(base + 1024, last)];
    float v2 = src[min(base + 2048, last)];
    float v3 = src[min(base + 3072, last)];
    float v4 = src[min(base + 4096, last)];
    float v5 = src[min(base + 5120, last)];
    float v6 = src[min(base + 6144, last)];
    float v7 = src[min(base + 7168, last)];
#define HIST1(U, VV) if (base + (U)*1024 < send) atomicAdd(&hist[fmono(VV) >> 20], 1u);
    HIST1(0, v0) HIST1(1, v1) HIST1(2, v2) HIST1(3, v3)
    HIST1(4, v4) HIST1(5, v5) HIST1(6, v6) HIST1(7, v7)
#undef HIST1
    __syncthreads();

    unsigned* gh = ghist + (size_t)(img * BPI + b) * 4096;
    for (int i = tid; i < 4096; i += 1024) gh[i] = hist[i];
}

// ---------- stage A2: gather + fused bstar (sums its level's private hists) ----------

__global__ __launch_bounds__(1024) void gather_kernel(const float* __restrict__ obj,
                                                      const unsigned* __restrict__ ghist,
                                                      unsigned long long* __restrict__ gcand,
                                                      int* __restrict__ gcnt,
                                                      int* __restrict__ gbstar) {
    __shared__ int s_misc[32];
    __shared__ int s_bstar, s_cnt;
    int img = blockIdx.x / BPI, b = blockIdx.x % BPI;
    int lvl = c_blvl[b], sl = c_bsl[b];
    int seg = img * BPI + b;
    int n = c_lvlN[lvl];
    int k = (lvl == 4) ? 507 : 1000;
    int s0 = sl * c_slsz[lvl];
    int send = min(s0 + c_slsz[lvl], n);
    const float* src = obj + (size_t)img * ATOT + c_lvlOff[lvl];
    int tid = threadIdx.x;
    int lane = tid & 63;

    if (tid == 0) s_cnt = 0;

    unsigned hx = 0, hy = 0, hz = 0, hw = 0;
    {
        int bs = c_bstart[lvl], bc = c_bcnt[lvl];
        for (int s = 0; s < bc; s++) {
            const uint4* gh4 = (const uint4*)(ghist + (size_t)(img * BPI + bs + s) * 4096);
            uint4 t = gh4[tid];
            hx += t.x; hy += t.y; hz += t.z; hw += t.w;
        }
    }
    int mysum = (int)(hx + hy + hz + hw);
    int excl = blockExclScan(mysum, s_misc);
    int target = n - k;
    {
        int P = excl;
        if ((int)hx > 0 && P <= target && target < P + (int)hx) s_bstar = 4 * tid + 0;
        P += (int)hx;
        if ((int)hy > 0 && P <= target && target < P + (int)hy) s_bstar = 4 * tid + 1;
        P += (int)hy;
        if ((int)hz > 0 && P <= target && target < P + (int)hz) s_bstar = 4 * tid + 2;
        P += (int)hz;
        if ((int)hw > 0 && P <= target && target < P + (int)hw) s_bstar = 4 * tid + 3;
    }
    __syncthreads();
    int bstar = s_bstar;
    if (tid == 0 && sl == 0) gbstar[img * 5 + lvl] = bstar;

    unsigned long long* gc = gcand + (size_t)seg * CAND_CAP;
    int base = s0 + tid, last = send - 1;
    float v0 = src[min(base,        last)];
    float v1 = src[min(base + 1024, last)];
    float v2 = src[min(base + 2048, last)];
    float v3 = src[min(base + 3072, last)];
    float v4 = src[min(base + 4096, last)];
    float v5 = src[min(base + 5120, last)];
    float v6 = src[min(base + 6144, last)];
    float v7 = src[min(base + 7168, last)];
#define PUSH1(U, VV)                                                                     \
    {                                                                                    \
        int ix = base + (U) * 1024;                                                      \
        unsigned key = fmono(VV);                                                        \
        bool s = (ix < send) && ((int)(key >> 20) >= bstar);                             \
        unsigned long long mk = __ballot(s);                                             \
        if (mk) {                                                                        \
            int pre = __popcll(mk & ((1ULL << lane) - 1ULL));                            \
            int ldr = __builtin_ctzll(mk);                                               \
            int basew = 0;                                                               \
            if (lane == ldr) basew = atomicAdd(&s_cnt, __popcll(mk));                    \
            basew = __shfl(basew, ldr);                                                  \
            if (s) {                                                                     \
                int pos = basew + pre;                                                   \
                if (pos < CAND_CAP)                                                      \
                    gc[pos] = ((unsigned long long)key << 32) | (unsigned)(~(unsigned)ix); \
            }                                                                            \
        }                                                                                \
    }
    PUSH1(0, v0) PUSH1(1, v1) PUSH1(2, v2) PUSH1(3, v3)
    PUSH1(4, v4) PUSH1(5, v5) PUSH1(6, v6) PUSH1(7, v7)
#undef PUSH1
    __syncthreads();
    if (tid == 0) gcnt[seg] = min(s_cnt, CAND_CAP);
}

// ---------- stage B (MEGA): topk-sort + decode + compact + mask + fixpoint NMS ----------
// One block per (img,lvl). Boxes and the pair-mask matrix live entirely in LDS.
// ck/subh alias the M region (sort completes before mask writes; barrier-separated).

__global__ __launch_bounds__(1024, 1) void mega_kernel(
    const float* __restrict__ deltas, const float* __restrict__ anchors,
    const unsigned long long* __restrict__ gcand, const int* __restrict__ gcnt,
    const int* __restrict__ gbstar,
    float* __restrict__ sx1, float* __restrict__ sy1, float* __restrict__ sx2,
    float* __restrict__ sy2, float* __restrict__ sscore,
    unsigned long long* __restrict__ ckey, int* __restrict__ cslot,
    unsigned long long* __restrict__ keepWords) {
    __shared__ __attribute__((aligned(16))) unsigned long long M[16384];  // 128 KB
    __shared__ float lx1[1024], ly1[1024], lx2[1024], ly2[1024], lar[1024];
    __shared__ int s_warp[32];
    __shared__ unsigned long long s_alive[16], s_kill[16];
    __shared__ int s_go, s_m, s_tot, s_sub, s_m2;

    unsigned long long* ck = M;                      // 4096 u64 = 32 KB
    unsigned* subh = (unsigned*)(M + 4096);          // 4096 u32 = 16 KB

    int grp = blockIdx.x;
    int img = grp / 5, lvl = grp % 5;
    int kn = (lvl == 4) ? 507 : 1000;
    int koff = lvl * 1000;
    int tid = threadIdx.x;
    int wv = tid >> 6, lane = tid & 63;

    // ---- phase A: concat segments ----
    int bs = c_bstart[lvl], bc = c_bcnt[lvl];
    int pref = 0;
    for (int s = 0; s < bc; s++) {
        int c = gcnt[img * BPI + bs + s];
        const unsigned long long* segp = gcand + (size_t)(img * BPI + bs + s) * CAND_CAP;
        for (int i = tid; i < c; i += 1024) {
            int d = pref + i;
            if (d < CAND_CAP) ck[d] = segp[i];
        }
        pref += c;
    }
    int m = min(pref, CAND_CAP);
    int bstarv = gbstar[grp];
    __syncthreads();

    // ---- 24-bit refine (drops sort size to 1024; same selected top-kn) ----
    int mm = m;
    if (m > 1024) {
        for (int i = tid; i < 4096; i += 1024) subh[i] = 0u;
        __syncthreads();
        int c0 = tid, c1 = tid + 1024, c2 = tid + 2048, c3 = tid + 3072;
        unsigned long long e0 = (c0 < m) ? ck[c0] : 0ULL;
        unsigned long long e1 = (c1 < m) ? ck[c1] : 0ULL;
        unsigned long long e2 = (c2 < m) ? ck[c2] : 0ULL;
        unsigned long long e3 = (c3 < m) ? ck[c3] : 0ULL;
        int hiCnt = 0;
#define CLS(E, C)                                                                        \
        if ((C) < m) {                                                                   \
            if ((unsigned)((E) >> 52) > (unsigned)bstarv) hiCnt++;                       \
            else atomicAdd(&subh[(unsigned)(((E) >> 40) & 0xFFFULL)], 1u);               \
        }
        CLS(e0, c0) CLS(e1, c1) CLS(e2, c2) CLS(e3, c3)
#undef CLS
        int exH = blockExclScan(hiCnt, s_warp);
        if (tid == 1023) s_tot = exH + hiCnt;
        __syncthreads();
        int cntHi = s_tot;
        int target2 = m - kn;
        const uint4* sh4 = (const uint4*)subh;
        uint4 sc = sh4[tid];
        int ms2 = (int)(sc.x + sc.y + sc.z + sc.w);
        int ex2 = blockExclScan(ms2, s_warp);
        {
            int Pp = ex2;
            if ((int)sc.x > 0 && Pp <= target2 && target2 < Pp + (int)sc.x) s_sub = 4 * tid + 0;
            Pp += (int)sc.x;
            if ((int)sc.y > 0 && Pp <= target2 && target2 < Pp + (int)sc.y) s_sub = 4 * tid + 1;
            Pp += (int)sc.y;
            if ((int)sc.z > 0 && Pp <= target2 && target2 < Pp + (int)sc.z) s_sub = 4 * tid + 2;
            Pp += (int)sc.z;
            if ((int)sc.w > 0 && Pp <= target2 && target2 < Pp + (int)sc.w) s_sub = 4 * tid + 3;
        }
        __syncthreads();
        int cstar = s_sub;
#define FLG(E, C)                                                                        \
        (((C) < m) && (((unsigned)((E) >> 52) > (unsigned)bstarv) ||                     \
                       ((unsigned)(((E) >> 40) & 0xFFFULL) >= (unsigned)cstar)))
        int f0 = FLG(e0, c0), f1 = FLG(e1, c1), f2 = FLG(e2, c2), f3 = FLG(e3, c3);
#undef FLG
        (void)cntHi;
        int fc = f0 + f1 + f2 + f3;
        int pos = blockExclScan(fc, s_warp);
        if (tid == 1023) s_m2 = pos + fc;
        __syncthreads();
        int m2 = s_m2;
        if (m2 <= 1024) {
            int p = pos;
            if (f0) ck[p++] = e0;
            if (f1) ck[p++] = e1;
            if (f2) ck[p++] = e2;
            if (f3) ck[p++] = e3;
            mm = m2;
        }
        __syncthreads();
    }

    // ---- bitonic sort ----
    int P = 512;
    while (P < mm) P <<= 1;
    for (int i = mm + tid; i < P; i += 1024) ck[i] = 0ULL;
    __syncthreads();
    for (unsigned kk = 2; kk <= (unsigned)P; kk <<= 1) {
        for (unsigned j = kk >> 1; j > 0; j >>= 1) {
            for (unsigned i = (unsigned)tid; i < (unsigned)P; i += 1024) {
                unsigned ixj = i ^ j;
                if (ixj > i) {
                    unsigned long long a = ck[i], b2 = ck[ixj];
                    bool up = ((i & kk) == 0);
                    if ((a > b2) == up) { ck[i] = b2; ck[ixj] = a; }
                }
            }
            __syncthreads();
        }
    }

    // ---- decode + compact valid boxes into LDS ----
    int r = tid;
    size_t o = (size_t)img * KTOT + koff + r;
    float x1 = 0.f, y1 = 0.f, x2 = 0.f, y2 = 0.f, s = 0.f;
    int valid = 0;
    if (r < kn) {
        unsigned long long key = ck[P - 1 - r];
        int idx = c_lvlOff[lvl] + (int)(~(unsigned)key);
        float logit = fmono_inv((unsigned)(key >> 32));
        float ef = (float)exp(-(double)logit);
        s = 1.0f / __fadd_rn(1.0f, ef);
        float a0 = anchors[(size_t)idx * 4 + 0], a1 = anchors[(size_t)idx * 4 + 1];
        float a2 = anchors[(size_t)idx * 4 + 2], a3 = anchors[(size_t)idx * 4 + 3];
        const float* dp = deltas + ((size_t)img * ATOT + idx) * 4;
        float dx = dp[0], dy = dp[1];
        const float BCLIP = 4.135166556742356f;  // log(1000/16)
        float dw = fminf(dp[2], BCLIP), dh = fminf(dp[3], BCLIP);
        float wa = __fsub_rn(a2, a0), ha = __fsub_rn(a3, a1);
        float cxa = __fadd_rn(a0, __fmul_rn(0.5f, wa));
        float cya = __fadd_rn(a1, __fmul_rn(0.5f, ha));
        float cx = __fadd_rn(__fmul_rn(dx, wa), cxa);
        float cy = __fadd_rn(__fmul_rn(dy, ha), cya);
        float w = __fmul_rn((float)exp((double)dw), wa);
        float h = __fmul_rn((float)exp((double)dh), ha);
        x1 = __fsub_rn(cx, __fmul_rn(0.5f, w));
        y1 = __fsub_rn(cy, __fmul_rn(0.5f, h));
        x2 = __fadd_rn(cx, __fmul_rn(0.5f, w));
        y2 = __fadd_rn(cy, __fmul_rn(0.5f, h));
        x1 = fminf(fmaxf(x1, 0.0f), 800.0f);
        y1 = fminf(fmaxf(y1, 0.0f), 800.0f);
        x2 = fminf(fmaxf(x2, 0.0f), 800.0f);
        y2 = fminf(fmaxf(y2, 0.0f), 800.0f);
        valid = (__fsub_rn(x2, x1) >= 0.001f) && (__fsub_rn(y2, y1) >= 0.001f) && (s >= 0.0f);
        sx1[o] = x1; sy1[o] = y1; sx2[o] = x2; sy2[o] = y2; sscore[o] = s;
    }
    int pos = blockExclScan(valid, s_warp);
    if (valid) {
        float lf = 1000.0f * (float)lvl;
        float ox1 = __fadd_rn(x1, lf);
        float oy1 = __fadd_rn(y1, lf);
        float ox2 = __fadd_rn(x2, lf);
        float oy2 = __fadd_rn(y2, lf);
        lx1[pos] = ox1; ly1[pos] = oy1; lx2[pos] = ox2; ly2[pos] = oy2;
        lar[pos] = __fmul_rn(__fsub_rn(ox2, ox1), __fsub_rn(oy2, oy1));
        int p = koff + r;
        size_t cb = (size_t)img * SLOTCAP + koff + pos;
        ckey[cb] = ((unsigned long long)fmono(s) << 32) | (unsigned)(~(unsigned)p);
        cslot[cb] = p;
    }
    if (tid == 1023) s_m = pos + valid;
    __syncthreads();  // boxes ready; ck no longer needed -> M reusable

    int mv = s_m;
    if (mv == 0) {
        if (tid < 16) keepWords[grp * 16 + tid] = 0ULL;
        return;
    }
    int W = (mv + 63) >> 6;
    int T = (W * (W + 1)) >> 1;

    // ---- mask build in LDS (row-major M[row*16+w], words w>=rowtile only) ----
    for (int t = wv; t < T; t += 16) {
        int w = (int)((sqrtf(8.0f * (float)t + 1.0f) - 1.0f) * 0.5f);
        while (((w + 1) * (w + 2)) / 2 <= t) w++;
        while ((w * (w + 1)) / 2 > t) w--;
        int c = t - ((w * (w + 1)) >> 1);

        int j = (w << 6) + lane;
        bool jv = j < mv;
        float jx1 = jv ? lx1[j] : 0.f, jy1 = jv ? ly1[j] : 0.f;
        float jx2 = jv ? lx2[j] : 0.f, jy2 = jv ? ly2[j] : 0.f;
        float jar = jv ? lar[j] : 0.f;

        unsigned long long myword = 0ULL;
        int i0 = c << 6, i1 = min(i0 + 64, mv);
        for (int i = i0; i < i1; i++) {
            float ix1 = lx1[i], iy1 = ly1[i], ix2 = lx2[i], iy2 = ly2[i], iar = lar[i];
            float ltx = fmaxf(ix1, jx1);
            float lty = fmaxf(iy1, jy1);
            float rbx = fminf(ix2, jx2);
            float rby = fminf(iy2, jy2);
            float wq = fmaxf(__fsub_rn(rbx, ltx), 0.0f);
            float hq = fmaxf(__fsub_rn(rby, lty), 0.0f);
            float inter = __fmul_rn(wq, hq);
            float uni = __fsub_rn(__fadd_rn(iar, jar), inter);
            float iou = inter / uni;  // keep IEEE div: decisions must match reference
            bool bit = jv && (j > i) && (iou > 0.7f);
            unsigned long long bal = __ballot(bit);
            if (lane == (i & 63)) myword = bal;
        }
        int irow = i0 + lane;
        if (irow < i1) M[irow * 16 + w] = myword;
    }

    // ---- fixpoint NMS (16 waves; rows strided by 64) ----
    int w16 = lane & 15, g = lane >> 4;
    int rowcls = wv * 4 + g;  // 0..63
    int fw = mv >> 6, tb = mv & 63;
    if (tid < 16) {
        s_alive[tid] = (tid < fw) ? ~0ULL : (tid == fw && tb) ? ((1ULL << tb) - 1ULL) : 0ULL;
        s_kill[tid] = 0ULL;
    }
    if (tid == 0) s_go = 1;
    __syncthreads();

    for (int it = 0; it <= mv && s_go; it++) {
        unsigned long long p = 0ULL;
        for (int rr = rowcls; rr < mv; rr += 64) {
            unsigned long long aw = s_alive[rr >> 6];
            unsigned long long bit = (aw >> (rr & 63)) & 1ULL;
            bit &= (unsigned long long)(w16 >= (rr >> 6));
            p |= M[rr * 16 + w16] & (0ULL - bit);
        }
        p |= shfl_u64(p, (lane + 32) & 63);
        p |= shfl_u64(p, (lane + 16) & 63);
        if (lane < 16 && p) atomicOr(&s_kill[lane], p);
        __syncthreads();
        if (wv == 0) {
            unsigned long long neww = 0ULL, oldw = 0ULL;
            if (lane < 16) {
                unsigned long long initw = (lane < fw) ? ~0ULL
                                          : (lane == fw && tb) ? ((1ULL << tb) - 1ULL) : 0ULL;
                oldw = s_alive[lane];
                neww = initw & ~s_kill[lane];
                s_alive[lane] = neww;
                s_kill[lane] = 0ULL;
            }
            unsigned long long ch = __ballot(lane < 16 && neww != oldw);
            if (lane == 0) s_go = (ch != 0ULL) ? 1 : 0;
        }
        __syncthreads();
    }
    if (tid < 16) keepWords[grp * 16 + tid] = s_alive[tid];
}

// ---------- stage D: fused 5-level compaction + global rank + output ----------

__global__ __launch_bounds__(1024) void scanout_kernel(
    const float* __restrict__ sx1, const float* __restrict__ sy1,
    const float* __restrict__ sx2, const float* __restrict__ sy2,
    const float* __restrict__ sscore,
    const unsigned long long* __restrict__ ckey, const int* __restrict__ cslot,
    const unsigned long long* __restrict__ keepWords, float* __restrict__ out) {
    __shared__ unsigned long long kkey[SLOTCAP];
    __shared__ int kslot[SLOTCAP];
    __shared__ int s_warp[32];
    __shared__ int s_pref[6];
    __shared__ int s_cnt[5];

    int img = blockIdx.x, tid = threadIdx.x;

    int f[5];
    int e0 = tid * 5;
    int cnt = 0;
#pragma unroll
    for (int c = 0; c < 5; c++) {
        int e = e0 + c;
        int fl = 0;
        if (e < 5000) {
            int lvl = e / 1000, rr = e - lvl * 1000;
            fl = (int)((keepWords[(img * 5 + lvl) * 16 + (rr >> 6)] >> (rr & 63)) & 1ULL);
        }
        f[c] = fl;
        cnt += fl;
    }
    int pos = blockExclScan(cnt, s_warp);
    {
        int run = pos;
#pragma unroll
        for (int c = 0; c < 5; c++) {
            int e = e0 + c;
            if (e < 5000 && (e - (e / 1000) * 1000) == 0) s_pref[e / 1000] = run;
            run += f[c];
        }
    }
    if (tid == 1023) s_pref[5] = pos + cnt;
    __syncthreads();
    {
        int run = pos;
#pragma unroll
        for (int c = 0; c < 5; c++) {
            int e = e0 + c;
            if (f[c]) {
                int lvl = e / 1000, rr = e - lvl * 1000;
                int pil = run - s_pref[lvl];
                size_t cb = (size_t)img * SLOTCAP + lvl * 1000 + rr;
                kkey[lvl * 1000 + pil] = ckey[cb];
                kslot[lvl * 1000 + pil] = cslot[cb];
            }
            run += f[c];
        }
    }
    if (tid < 5) s_cnt[tid] = s_pref[tid + 1] - s_pref[tid];
    __syncthreads();

    int tK = s_pref[5];

    for (int lvl = 0; lvl < 5; lvl++) {
        int Kc = s_cnt[lvl];
        int koff = lvl * 1000;
        for (int q = tid; q < Kc; q += 1024) {
            unsigned long long key = kkey[koff + q];
            int rank = q;
#pragma unroll
            for (int ol = 0; ol < 5; ol++) {
                if (ol == lvl) continue;
                int lo = 0, hi = s_cnt[ol], base = ol * 1000;
                while (lo < hi) {
                    int mid = (lo + hi) >> 1;
                    if (kkey[base + mid] > key) lo = mid + 1; else hi = mid;
                }
                rank += lo;
            }
            if (rank < POSTN) {
                int slot = kslot[koff + q];
                size_t o = (size_t)img * KTOT + slot;
                float* dst = out + ((size_t)img * POSTN + rank) * 5;
                dst[0] = sx1[o]; dst[1] = sy1[o]; dst[2] = sx2[o]; dst[3] = sy2[o];
                dst[4] = sscore[o];
            }
        }
    }

    int z0 = tK < POSTN ? tK : POSTN;
    int nz = (POSTN - z0) * 5;
    float* ob = out + (size_t)img * POSTN * 5 + (size_t)z0 * 5;
    for (int u = tid; u < nz; u += 1024) ob[u] = 0.f;
}

// ---------- host ----------

extern "C" void kernel_launch(void* const* d_in, const int* in_sizes, int n_in,
                              void* d_out, int out_size, void* d_ws, size_t ws_size,
                              hipStream_t stream) {
    const float* obj = (const float*)d_in[0];
    const float* deltas = (const float*)d_in[1];
    const float* anchors = (const float*)d_in[2];
    float* out = (float*)d_out;

    char* ws = (char*)d_ws;
    size_t off = 0;
    auto alloc = [&](size_t bytes) {
        size_t o = off;
        off += (bytes + 255) & ~(size_t)255;
        return o;
    };
    unsigned* ghist = (unsigned*)(ws + alloc((size_t)NIMG * BPI * 4096 * 4));
    int* gcnt = (int*)(ws + alloc((size_t)NIMG * BPI * 4));
    int* gbstar = (int*)(ws + alloc((size_t)NIMG * 5 * 4));
    unsigned long long* gcand =
        (unsigned long long*)(ws + alloc((size_t)NIMG * BPI * CAND_CAP * 8));
    float* sx1 = (float*)(ws + alloc((size_t)NIMG * KTOT * 4));
    float* sy1 = (float*)(ws + alloc((size_t)NIMG * KTOT * 4));
    float* sx2 = (float*)(ws + alloc((size_t)NIMG * KTOT * 4));
    float* sy2 = (float*)(ws + alloc((size_t)NIMG * KTOT * 4));
    float* sscore = (float*)(ws + alloc((size_t)NIMG * KTOT * 4));
    unsigned long long* ckey = (unsigned long long*)(ws + alloc((size_t)NIMG * SLOTCAP * 8));
    int* cslot = (int*)(ws + alloc((size_t)NIMG * SLOTCAP * 4));
    unsigned long long* keepWords = (unsigned long long*)(ws + alloc((size_t)NIMG * 5 * 16 * 8));

    hist_kernel<<<dim3(NIMG * BPI), dim3(1024), 0, stream>>>(obj, ghist);
    gather_kernel<<<dim3(NIMG * BPI), dim3(1024), 0, stream>>>(obj, ghist, gcand, gcnt,
                                                               gbstar);
    mega_kernel<<<dim3(NIMG * 5), dim3(1024), 0, stream>>>(
        deltas, anchors, gcand, gcnt, gbstar, sx1, sy1, sx2, sy2, sscore,
        ckey, cslot, keepWords);
    scanout_kernel<<<dim3(NIMG), dim3(1024), 0, stream>>>(
        sx1, sy1, sx2, sy2, sscore, ckey, cslot, keepWords, out);
}

// Round 16
// 162.343 us; speedup vs baseline: 1.6366x; 1.6366x over previous
//
#include <hip/hip_runtime.h>
#include <stdint.h>

#define KTOT 4507
#define POSTN 1000
#define ATOT 159882
#define NIMG 4
#define CAND_CAP 4096
#define SLOTCAP 5000  // per-image compact capacity (koff spacing = lvl*1000)
#define BPI 22        // hist/gather blocks per image: 15+4+1+1+1
#define MT_IMG 73728  // per-image mask words: 4*(1024*16) + 512*16

// ---------- helpers ----------

__device__ inline unsigned fmono(float f) {
    unsigned u = __float_as_uint(f);
    return (u & 0x80000000u) ? ~u : (u | 0x80000000u);
}
__device__ inline float fmono_inv(unsigned u) {
    unsigned b = (u & 0x80000000u) ? (u ^ 0x80000000u) : ~u;
    return __uint_as_float(b);
}

__device__ inline unsigned long long shfl_u64(unsigned long long v, int src) {
    int lo = __shfl((int)(unsigned)(v & 0xFFFFFFFFULL), src);
    int hi = __shfl((int)(unsigned)(v >> 32), src);
    return ((unsigned long long)(unsigned)hi << 32) | (unsigned)lo;
}

// async global->LDS DMA, 16 B per lane (gfx950)
__device__ inline void async16(unsigned long long* lds, const unsigned long long* g) {
#if __has_builtin(__builtin_amdgcn_global_load_lds)
    __builtin_amdgcn_global_load_lds(
        (const __attribute__((address_space(1))) unsigned*)g,
        (__attribute__((address_space(3))) unsigned*)lds, 16, 0, 0);
#else
    *(ulonglong2*)lds = *(const ulonglong2*)g;
#endif
}

// exclusive prefix over a 1024-thread block; warpSums = LDS int[>=16]; call uniformly.
__device__ inline int blockExclScan(int v, int* warpSums) {
    int tid = threadIdx.x;
    int lane = tid & 63, wid = tid >> 6;
    int x = v;
#pragma unroll
    for (int d = 1; d < 64; d <<= 1) {
        int y = __shfl_up(x, d);
        if (lane >= d) x += y;
    }
    if (lane == 63) warpSums[wid] = x;
    __syncthreads();
    if (wid == 0) {
        int s = (lane < 16) ? warpSums[lane] : 0;
#pragma unroll
        for (int d = 1; d < 16; d <<= 1) {
            int y = __shfl_up(s, d);
            if (lane >= d) s += y;
        }
        if (lane < 16) warpSums[lane] = s;
    }
    __syncthreads();
    int wpre = (wid == 0) ? 0 : warpSums[wid - 1];
    return wpre + (x - v);
}

__device__ __constant__ int c_lvlOff[5] = {0, 120000, 150000, 157500, 159375};
__device__ __constant__ int c_lvlN[5]   = {120000, 30000, 7500, 1875, 507};
__device__ __constant__ int c_slsz[5]   = {8000, 7500, 7500, 1875, 507};
__device__ __constant__ int c_blvl[BPI] = {0,0,0,0,0,0,0,0,0,0,0,0,0,0,0, 1,1,1,1, 2, 3, 4};
__device__ __constant__ int c_bsl[BPI]  = {0,1,2,3,4,5,6,7,8,9,10,11,12,13,14, 0,1,2,3, 0, 0, 0};
__device__ __constant__ int c_bstart[5] = {0, 15, 19, 20, 21};
__device__ __constant__ int c_bcnt[5]   = {15, 4, 1, 1, 1};

// row-major mask: MT[row*16 + w]; lvl<4 -> 1024 rows, lvl4 -> 512 rows
__device__ inline size_t mtBase(int img, int lvl) {
    return (size_t)img * MT_IMG + (lvl < 4 ? (size_t)lvl * 16384 : 65536);
}

// ---------- stage A1: sliced histogram -> PRIVATE per-segment hist (no atomics) ----------

__global__ __launch_bounds__(1024) void hist_kernel(const float* __restrict__ obj,
                                                    unsigned* __restrict__ ghist) {
    __shared__ unsigned hist[4096];
    int img = blockIdx.x / BPI, b = blockIdx.x % BPI;
    int lvl = c_blvl[b], sl = c_bsl[b];
    int n = c_lvlN[lvl];
    int s0 = sl * c_slsz[lvl];
    int send = min(s0 + c_slsz[lvl], n);
    const float* src = obj + (size_t)img * ATOT + c_lvlOff[lvl];
    int tid = threadIdx.x;

    for (int i = tid; i < 4096; i += 1024) hist[i] = 0u;
    __syncthreads();

    int base = s0 + tid, last = send - 1;
    float v0 = src[min(base,        last)];
    float v1 = src[min(base + 1024, last)];
    float v2 = src[min(base + 2048, last)];
    float v3 = src[min(base + 3072, last)];
    float v4 = src[min(base + 4096, last)];
    float v5 = src[min(base + 5120, last)];
    float v6 = src[min(base + 6144, last)];
    float v7 = src[min(base + 7168, last)];
#define HIST1(U, VV) if (base + (U)*1024 < send) atomicAdd(&hist[fmono(VV) >> 20], 1u);
    HIST1(0, v0) HIST1(1, v1) HIST1(2, v2) HIST1(3, v3)
    HIST1(4, v4) HIST1(5, v5) HIST1(6, v6) HIST1(7, v7)
#undef HIST1
    __syncthreads();

    unsigned* gh = ghist + (size_t)(img * BPI + b) * 4096;
    for (int i = tid; i < 4096; i += 1024) gh[i] = hist[i];
}

// ---------- stage A2: gather + fused bstar (sums its level's private hists) ----------

__global__ __launch_bounds__(1024) void gather_kernel(const float* __restrict__ obj,
                                                      const unsigned* __restrict__ ghist,
                                                      unsigned long long* __restrict__ gcand,
                                                      int* __restrict__ gcnt,
                                                      int* __restrict__ gbstar) {
    __shared__ int s_misc[32];
    __shared__ int s_bstar, s_cnt;
    int img = blockIdx.x / BPI, b = blockIdx.x % BPI;
    int lvl = c_blvl[b], sl = c_bsl[b];
    int seg = img * BPI + b;
    int n = c_lvlN[lvl];
    int k = (lvl == 4) ? 507 : 1000;
    int s0 = sl * c_slsz[lvl];
    int send = min(s0 + c_slsz[lvl], n);
    const float* src = obj + (size_t)img * ATOT + c_lvlOff[lvl];
    int tid = threadIdx.x;
    int lane = tid & 63;

    if (tid == 0) s_cnt = 0;

    // sum this level's per-segment histograms (<=15 independent uint4 loads, L2-hot)
    unsigned hx = 0, hy = 0, hz = 0, hw = 0;
    {
        int bs = c_bstart[lvl], bc = c_bcnt[lvl];
        for (int s = 0; s < bc; s++) {
            const uint4* gh4 = (const uint4*)(ghist + (size_t)(img * BPI + bs + s) * 4096);
            uint4 t = gh4[tid];
            hx += t.x; hy += t.y; hz += t.z; hw += t.w;
        }
    }
    int mysum = (int)(hx + hy + hz + hw);
    int excl = blockExclScan(mysum, s_misc);
    int target = n - k;
    {
        int P = excl;
        if ((int)hx > 0 && P <= target && target < P + (int)hx) s_bstar = 4 * tid + 0;
        P += (int)hx;
        if ((int)hy > 0 && P <= target && target < P + (int)hy) s_bstar = 4 * tid + 1;
        P += (int)hy;
        if ((int)hz > 0 && P <= target && target < P + (int)hz) s_bstar = 4 * tid + 2;
        P += (int)hz;
        if ((int)hw > 0 && P <= target && target < P + (int)hw) s_bstar = 4 * tid + 3;
    }
    __syncthreads();
    int bstar = s_bstar;
    if (tid == 0 && sl == 0) gbstar[img * 5 + lvl] = bstar;

    unsigned long long* gc = gcand + (size_t)seg * CAND_CAP;
    int base = s0 + tid, last = send - 1;
    float v0 = src[min(base,        last)];
    float v1 = src[min(base + 1024, last)];
    float v2 = src[min(base + 2048, last)];
    float v3 = src[min(base + 3072, last)];
    float v4 = src[min(base + 4096, last)];
    float v5 = src[min(base + 5120, last)];
    float v6 = src[min(base + 6144, last)];
    float v7 = src[min(base + 7168, last)];
#define PUSH1(U, VV)                                                                     \
    {                                                                                    \
        int ix = base + (U) * 1024;                                                      \
        unsigned key = fmono(VV);                                                        \
        bool s = (ix < send) && ((int)(key >> 20) >= bstar);                             \
        unsigned long long mk = __ballot(s);                                             \
        if (mk) {                                                                        \
            int pre = __popcll(mk & ((1ULL << lane) - 1ULL));                            \
            int ldr = __builtin_ctzll(mk);                                               \
            int basew = 0;                                                               \
            if (lane == ldr) basew = atomicAdd(&s_cnt, __popcll(mk));                    \
            basew = __shfl(basew, ldr);                                                  \
            if (s) {                                                                     \
                int pos = basew + pre;                                                   \
                if (pos < CAND_CAP)                                                      \
                    gc[pos] = ((unsigned long long)key << 32) | (unsigned)(~(unsigned)ix); \
            }                                                                            \
        }                                                                                \
    }
    PUSH1(0, v0) PUSH1(1, v1) PUSH1(2, v2) PUSH1(3, v3)
    PUSH1(4, v4) PUSH1(5, v5) PUSH1(6, v6) PUSH1(7, v7)
#undef PUSH1
    __syncthreads();
    if (tid == 0) gcnt[seg] = min(s_cnt, CAND_CAP);
}

// ---------- stage B: concat + 24-bit refine + bitonic sort + decode + compaction ----------

__global__ __launch_bounds__(1024) void rankdecode_kernel(
    const float* __restrict__ deltas, const float* __restrict__ anchors,
    const unsigned long long* __restrict__ gcand, const int* __restrict__ gcnt,
    const int* __restrict__ gbstar,
    float* __restrict__ sx1, float* __restrict__ sy1, float* __restrict__ sx2,
    float* __restrict__ sy2, float* __restrict__ sscore,
    float* __restrict__ cx1, float* __restrict__ cy1, float* __restrict__ cx2,
    float* __restrict__ cy2, float* __restrict__ car,
    unsigned long long* __restrict__ ckey, int* __restrict__ cslot, int* __restrict__ cm) {
    __shared__ unsigned long long ck[CAND_CAP];
    __shared__ __attribute__((aligned(16))) unsigned subh[4096];
    __shared__ int s_warp[32];
    __shared__ int s_tot, s_sub, s_m2;

    int grp = blockIdx.x;
    int img = grp / 5, lvl = grp % 5;
    int kn = (lvl == 4) ? 507 : 1000;
    int koff = lvl * 1000;
    int tid = threadIdx.x;

    int bs = c_bstart[lvl], bc = c_bcnt[lvl];
    int pref = 0;
    for (int s = 0; s < bc; s++) {
        int c = gcnt[img * BPI + bs + s];
        const unsigned long long* segp = gcand + (size_t)(img * BPI + bs + s) * CAND_CAP;
        for (int i = tid; i < c; i += 1024) {
            int d = pref + i;
            if (d < CAND_CAP) ck[d] = segp[i];
        }
        pref += c;
    }
    int m = min(pref, CAND_CAP);
    int bstarv = gbstar[grp];
    __syncthreads();

    // refine threshold to 24 bits so the sort size drops to 1024 (selected set
    // contains the exact top-kn; keys distinct -> identical emitted order)
    int mm = m;
    if (m > 1024) {
        for (int i = tid; i < 4096; i += 1024) subh[i] = 0u;
        __syncthreads();
        int c0 = tid, c1 = tid + 1024, c2 = tid + 2048, c3 = tid + 3072;
        unsigned long long e0 = (c0 < m) ? ck[c0] : 0ULL;
        unsigned long long e1 = (c1 < m) ? ck[c1] : 0ULL;
        unsigned long long e2 = (c2 < m) ? ck[c2] : 0ULL;
        unsigned long long e3 = (c3 < m) ? ck[c3] : 0ULL;
        int hiCnt = 0;
#define CLS(E, C)                                                                        \
        if ((C) < m) {                                                                   \
            if ((unsigned)((E) >> 52) > (unsigned)bstarv) hiCnt++;                       \
            else atomicAdd(&subh[(unsigned)(((E) >> 40) & 0xFFFULL)], 1u);               \
        }
        CLS(e0, c0) CLS(e1, c1) CLS(e2, c2) CLS(e3, c3)
#undef CLS
        int exH = blockExclScan(hiCnt, s_warp);
        if (tid == 1023) s_tot = exH + hiCnt;
        __syncthreads();
        int cntHi = s_tot;
        int target2 = (m - cntHi) - (kn - cntHi);  // = m - kn
        const uint4* sh4 = (const uint4*)subh;
        uint4 sc = sh4[tid];
        int ms2 = (int)(sc.x + sc.y + sc.z + sc.w);
        int ex2 = blockExclScan(ms2, s_warp);
        {
            int Pp = ex2;
            if ((int)sc.x > 0 && Pp <= target2 && target2 < Pp + (int)sc.x) s_sub = 4 * tid + 0;
            Pp += (int)sc.x;
            if ((int)sc.y > 0 && Pp <= target2 && target2 < Pp + (int)sc.y) s_sub = 4 * tid + 1;
            Pp += (int)sc.y;
            if ((int)sc.z > 0 && Pp <= target2 && target2 < Pp + (int)sc.z) s_sub = 4 * tid + 2;
            Pp += (int)sc.z;
            if ((int)sc.w > 0 && Pp <= target2 && target2 < Pp + (int)sc.w) s_sub = 4 * tid + 3;
        }
        __syncthreads();
        int cstar = s_sub;
#define FLG(E, C)                                                                        \
        (((C) < m) && (((unsigned)((E) >> 52) > (unsigned)bstarv) ||                     \
                       ((unsigned)(((E) >> 40) & 0xFFFULL) >= (unsigned)cstar)))
        int f0 = FLG(e0, c0), f1 = FLG(e1, c1), f2 = FLG(e2, c2), f3 = FLG(e3, c3);
#undef FLG
        int fc = f0 + f1 + f2 + f3;
        int pos = blockExclScan(fc, s_warp);
        if (tid == 1023) s_m2 = pos + fc;
        __syncthreads();
        int m2 = s_m2;
        if (m2 <= 1024) {  // scatter pruned set to front (order irrelevant pre-sort)
            int p = pos;
            if (f0) ck[p++] = e0;
            if (f1) ck[p++] = e1;
            if (f2) ck[p++] = e2;
            if (f3) ck[p++] = e3;
            mm = m2;
        }
        __syncthreads();
    }

    int P = 512;
    while (P < mm) P <<= 1;
    for (int i = mm + tid; i < P; i += 1024) ck[i] = 0ULL;
    __syncthreads();

    for (unsigned kk = 2; kk <= (unsigned)P; kk <<= 1) {
        for (unsigned j = kk >> 1; j > 0; j >>= 1) {
            for (unsigned i = (unsigned)tid; i < (unsigned)P; i += 1024) {
                unsigned ixj = i ^ j;
                if (ixj > i) {
                    unsigned long long a = ck[i], b2 = ck[ixj];
                    bool up = ((i & kk) == 0);
                    if ((a > b2) == up) { ck[i] = b2; ck[ixj] = a; }
                }
            }
            __syncthreads();
        }
    }

    int r = tid;
    size_t o = (size_t)img * KTOT + koff + r;
    float x1 = 0.f, y1 = 0.f, x2 = 0.f, y2 = 0.f, s = 0.f;
    int valid = 0;
    if (r < kn) {
        unsigned long long key = ck[P - 1 - r];
        int idx = c_lvlOff[lvl] + (int)(~(unsigned)key);
        float logit = fmono_inv((unsigned)(key >> 32));
        float ef = (float)exp(-(double)logit);
        s = 1.0f / __fadd_rn(1.0f, ef);
        float a0 = anchors[(size_t)idx * 4 + 0], a1 = anchors[(size_t)idx * 4 + 1];
        float a2 = anchors[(size_t)idx * 4 + 2], a3 = anchors[(size_t)idx * 4 + 3];
        const float* dp = deltas + ((size_t)img * ATOT + idx) * 4;
        float dx = dp[0], dy = dp[1];
        const float BCLIP = 4.135166556742356f;  // log(1000/16)
        float dw = fminf(dp[2], BCLIP), dh = fminf(dp[3], BCLIP);
        float wa = __fsub_rn(a2, a0), ha = __fsub_rn(a3, a1);
        float cxa = __fadd_rn(a0, __fmul_rn(0.5f, wa));
        float cya = __fadd_rn(a1, __fmul_rn(0.5f, ha));
        float cx = __fadd_rn(__fmul_rn(dx, wa), cxa);
        float cy = __fadd_rn(__fmul_rn(dy, ha), cya);
        float w = __fmul_rn((float)exp((double)dw), wa);
        float h = __fmul_rn((float)exp((double)dh), ha);
        x1 = __fsub_rn(cx, __fmul_rn(0.5f, w));
        y1 = __fsub_rn(cy, __fmul_rn(0.5f, h));
        x2 = __fadd_rn(cx, __fmul_rn(0.5f, w));
        y2 = __fadd_rn(cy, __fmul_rn(0.5f, h));
        x1 = fminf(fmaxf(x1, 0.0f), 800.0f);
        y1 = fminf(fmaxf(y1, 0.0f), 800.0f);
        x2 = fminf(fmaxf(x2, 0.0f), 800.0f);
        y2 = fminf(fmaxf(y2, 0.0f), 800.0f);
        valid = (__fsub_rn(x2, x1) >= 0.001f) && (__fsub_rn(y2, y1) >= 0.001f) && (s >= 0.0f);
        sx1[o] = x1; sy1[o] = y1; sx2[o] = x2; sy2[o] = y2; sscore[o] = s;
    }

    int pos = blockExclScan(valid, s_warp);
    if (valid) {
        float lf = 1000.0f * (float)lvl;
        size_t cb = (size_t)img * SLOTCAP + koff + pos;
        float ox1 = __fadd_rn(x1, lf);
        float oy1 = __fadd_rn(y1, lf);
        float ox2 = __fadd_rn(x2, lf);
        float oy2 = __fadd_rn(y2, lf);
        cx1[cb] = ox1; cy1[cb] = oy1; cx2[cb] = ox2; cy2[cb] = oy2;
        car[cb] = __fmul_rn(__fsub_rn(ox2, ox1), __fsub_rn(oy2, oy1));
        int p = koff + r;
        ckey[cb] = ((unsigned long long)fmono(s) << 32) | (unsigned)(~(unsigned)p);
        cslot[cb] = p;
    }
    if (tid == 1023) cm[grp] = pos + valid;
}

// ---------- stage C: mask build (ROW-MAJOR, words w in [rowtile, W) per row) ----------

__global__ __launch_bounds__(512) void mask_kernel(
    const float* __restrict__ cx1, const float* __restrict__ cy1,
    const float* __restrict__ cx2, const float* __restrict__ cy2,
    const float* __restrict__ car, const int* __restrict__ cm,
    unsigned long long* __restrict__ maskT) {
    __shared__ float lx1[1000], ly1[1000], lx2[1000], ly2[1000], lar[1000];
    int iq = blockIdx.y;
    int img = iq / 5, lvl = iq % 5;
    int m = cm[iq];
    int W = (m + 63) >> 6;
    int T = (W * (W + 1)) >> 1;
    int tbase = blockIdx.x * 8;
    if (tbase >= T) return;

    size_t cb0 = (size_t)img * SLOTCAP + lvl * 1000;
    for (int q = threadIdx.x; q < m; q += 512) {
        lx1[q] = cx1[cb0 + q]; ly1[q] = cy1[cb0 + q];
        lx2[q] = cx2[cb0 + q]; ly2[q] = cy2[cb0 + q];
        lar[q] = car[cb0 + q];
    }
    __syncthreads();

    int wv = threadIdx.x >> 6, lane = threadIdx.x & 63;
    int t = tbase + wv;
    if (t >= T) return;
    int w = (int)((sqrtf(8.0f * (float)t + 1.0f) - 1.0f) * 0.5f);
    while (((w + 1) * (w + 2)) / 2 <= t) w++;
    while ((w * (w + 1)) / 2 > t) w--;
    int c = t - ((w * (w + 1)) >> 1);

    unsigned long long* MT = maskT + mtBase(img, lvl);

    int j = (w << 6) + lane;
    bool jv = j < m;
    float jx1 = jv ? lx1[j] : 0.f, jy1 = jv ? ly1[j] : 0.f;
    float jx2 = jv ? lx2[j] : 0.f, jy2 = jv ? ly2[j] : 0.f;
    float jar = jv ? lar[j] : 0.f;

    unsigned long long myword = 0ULL;
    int i0 = c << 6, i1 = min(i0 + 64, m);
    for (int i = i0; i < i1; i++) {
        float ix1 = lx1[i], iy1 = ly1[i], ix2 = lx2[i], iy2 = ly2[i], iar = lar[i];
        float ltx = fmaxf(ix1, jx1);
        float lty = fmaxf(iy1, jy1);
        float rbx = fminf(ix2, jx2);
        float rby = fminf(iy2, jy2);
        float wq = fmaxf(__fsub_rn(rbx, ltx), 0.0f);
        float hq = fmaxf(__fsub_rn(rby, lty), 0.0f);
        float inter = __fmul_rn(wq, hq);
        float uni = __fsub_rn(__fadd_rn(iar, jar), inter);
        float iou = inter / uni;  // keep IEEE div: decisions must match reference exactly
        bool bit = jv && (j > i) && (iou > 0.7f);
        unsigned long long bal = __ballot(bit);
        if (lane == (i & 63)) myword = bal;
    }
    int irow = i0 + lane;
    if (irow < i1) MT[(size_t)irow * 16 + w] = myword;
}

// ---------- stage C2: greedy NMS as antitone FIXPOINT (no serial recurrence) ----------

__global__ __launch_bounds__(256, 1) void scan_kernel(
    const unsigned long long* __restrict__ maskT, const int* __restrict__ cm,
    unsigned long long* __restrict__ keepWords) {
    __shared__ unsigned long long M[16384];  // 128 KB staged mask (row-major, stride 16)
    __shared__ unsigned long long s_alive[16], s_kill[16];
    __shared__ int s_go;
    int grp = blockIdx.x;
    int img = grp / 5, lvl = grp % 5;
    int m = cm[grp];
    int tid = threadIdx.x;
    int wv = tid >> 6, lane = tid & 63;
    int w16 = lane & 15, g = lane >> 4;
    int rowgrp = wv * 4 + g;  // 0..15

    if (m == 0) {
        if (tid < 16) keepWords[grp * 16 + tid] = 0ULL;
        return;
    }

    const unsigned long long* src = maskT + mtBase(img, lvl);
    int rounds = (m * 16 + 511) >> 9;
    for (int k = 0; k < rounds; k++) {
        int u = (k << 9) + tid * 2;
        async16(&M[u], &src[u]);
    }
    int fw = m >> 6, tb = m & 63;
    if (tid < 16) {
        unsigned long long a = (tid < fw) ? ~0ULL
                              : (tid == fw && tb) ? ((1ULL << tb) - 1ULL) : 0ULL;
        s_alive[tid] = a;
        s_kill[tid] = 0ULL;
    }
    if (tid == 0) s_go = 1;
    __syncthreads();  // drains DMA

    for (int it = 0; it <= m && s_go; it++) {
        unsigned long long p = 0ULL;
        for (int r = rowgrp; r < m; r += 16) {
            unsigned long long aw = s_alive[r >> 6];
            unsigned long long bit = (aw >> (r & 63)) & 1ULL;
            bit &= (unsigned long long)(w16 >= (r >> 6));
            p |= M[r * 16 + w16] & (0ULL - bit);
        }
        p |= shfl_u64(p, (lane + 32) & 63);
        p |= shfl_u64(p, (lane + 16) & 63);
        if (lane < 16 && p) atomicOr(&s_kill[lane], p);
        __syncthreads();
        if (wv == 0) {
            unsigned long long neww = 0ULL, oldw = 0ULL;
            if (lane < 16) {
                unsigned long long initw = (lane < fw) ? ~0ULL
                                          : (lane == fw && tb) ? ((1ULL << tb) - 1ULL) : 0ULL;
                oldw = s_alive[lane];
                neww = initw & ~s_kill[lane];
                s_alive[lane] = neww;
                s_kill[lane] = 0ULL;
            }
            unsigned long long ch = __ballot(lane < 16 && neww != oldw);
            if (lane == 0) s_go = (ch != 0ULL) ? 1 : 0;
        }
        __syncthreads();
    }
    if (tid < 16) keepWords[grp * 16 + tid] = s_alive[tid];
}

// ---------- stage D: fused 5-level compaction + global rank + output ----------

__global__ __launch_bounds__(1024) void scanout_kernel(
    const float* __restrict__ sx1, const float* __restrict__ sy1,
    const float* __restrict__ sx2, const float* __restrict__ sy2,
    const float* __restrict__ sscore,
    const unsigned long long* __restrict__ ckey, const int* __restrict__ cslot,
    const unsigned long long* __restrict__ keepWords, float* __restrict__ out) {
    __shared__ unsigned long long kkey[SLOTCAP];
    __shared__ int kslot[SLOTCAP];
    __shared__ int s_warp[32];
    __shared__ int s_pref[6];
    __shared__ int s_cnt[5];

    int img = blockIdx.x, tid = threadIdx.x;

    // one concatenated scan over all 5 levels' keep flags (level-major, 5/thread).
    // keepWords bits >= m are provably 0 (fixpoint alive init masks to m bits).
    int f[5];
    int e0 = tid * 5;
    int cnt = 0;
#pragma unroll
    for (int c = 0; c < 5; c++) {
        int e = e0 + c;
        int fl = 0;
        if (e < 5000) {
            int lvl = e / 1000, rr = e - lvl * 1000;
            fl = (int)((keepWords[(img * 5 + lvl) * 16 + (rr >> 6)] >> (rr & 63)) & 1ULL);
        }
        f[c] = fl;
        cnt += fl;
    }
    int pos = blockExclScan(cnt, s_warp);
    {
        int run = pos;
#pragma unroll
        for (int c = 0; c < 5; c++) {
            int e = e0 + c;
            if (e < 5000 && (e - (e / 1000) * 1000) == 0) s_pref[e / 1000] = run;
            run += f[c];
        }
    }
    if (tid == 1023) s_pref[5] = pos + cnt;
    __syncthreads();
    {
        int run = pos;
#pragma unroll
        for (int c = 0; c < 5; c++) {
            int e = e0 + c;
            if (f[c]) {
                int lvl = e / 1000, rr = e - lvl * 1000;
                int pil = run - s_pref[lvl];
                size_t cb = (size_t)img * SLOTCAP + lvl * 1000 + rr;
                kkey[lvl * 1000 + pil] = ckey[cb];
                kslot[lvl * 1000 + pil] = cslot[cb];
            }
            run += f[c];
        }
    }
    if (tid < 5) s_cnt[tid] = s_pref[tid + 1] - s_pref[tid];
    __syncthreads();

    int tK = s_pref[5];

    for (int lvl = 0; lvl < 5; lvl++) {
        int Kc = s_cnt[lvl];
        int koff = lvl * 1000;
        for (int q = tid; q < Kc; q += 1024) {
            unsigned long long key = kkey[koff + q];
            int rank = q;
#pragma unroll
            for (int ol = 0; ol < 5; ol++) {
                if (ol == lvl) continue;
                int lo = 0, hi = s_cnt[ol], base = ol * 1000;
                while (lo < hi) {
                    int mid = (lo + hi) >> 1;
                    if (kkey[base + mid] > key) lo = mid + 1; else hi = mid;
                }
                rank += lo;
            }
            if (rank < POSTN) {
                int slot = kslot[koff + q];
                size_t o = (size_t)img * KTOT + slot;
                float* dst = out + ((size_t)img * POSTN + rank) * 5;
                dst[0] = sx1[o]; dst[1] = sy1[o]; dst[2] = sx2[o]; dst[3] = sy2[o];
                dst[4] = sscore[o];
            }
        }
    }

    int z0 = tK < POSTN ? tK : POSTN;
    int nz = (POSTN - z0) * 5;
    float* ob = out + (size_t)img * POSTN * 5 + (size_t)z0 * 5;
    for (int u = tid; u < nz; u += 1024) ob[u] = 0.f;
}

// ---------- host ----------

extern "C" void kernel_launch(void* const* d_in, const int* in_sizes, int n_in,
                              void* d_out, int out_size, void* d_ws, size_t ws_size,
                              hipStream_t stream) {
    const float* obj = (const float*)d_in[0];
    const float* deltas = (const float*)d_in[1];
    const float* anchors = (const float*)d_in[2];
    float* out = (float*)d_out;

    char* ws = (char*)d_ws;
    size_t off = 0;
    auto alloc = [&](size_t bytes) {
        size_t o = off;
        off += (bytes + 255) & ~(size_t)255;
        return o;
    };
    unsigned* ghist = (unsigned*)(ws + alloc((size_t)NIMG * BPI * 4096 * 4));
    int* gcnt = (int*)(ws + alloc((size_t)NIMG * BPI * 4));
    int* gbstar = (int*)(ws + alloc((size_t)NIMG * 5 * 4));
    unsigned long long* gcand =
        (unsigned long long*)(ws + alloc((size_t)NIMG * BPI * CAND_CAP * 8));
    float* sx1 = (float*)(ws + alloc((size_t)NIMG * KTOT * 4));
    float* sy1 = (float*)(ws + alloc((size_t)NIMG * KTOT * 4));
    float* sx2 = (float*)(ws + alloc((size_t)NIMG * KTOT * 4));
    float* sy2 = (float*)(ws + alloc((size_t)NIMG * KTOT * 4));
    float* sscore = (float*)(ws + alloc((size_t)NIMG * KTOT * 4));
    float* cx1 = (float*)(ws + alloc((size_t)NIMG * SLOTCAP * 4));
    float* cy1 = (float*)(ws + alloc((size_t)NIMG * SLOTCAP * 4));
    float* cx2 = (float*)(ws + alloc((size_t)NIMG * SLOTCAP * 4));
    float* cy2 = (float*)(ws + alloc((size_t)NIMG * SLOTCAP * 4));
    float* car = (float*)(ws + alloc((size_t)NIMG * SLOTCAP * 4));
    unsigned long long* ckey = (unsigned long long*)(ws + alloc((size_t)NIMG * SLOTCAP * 8));
    int* cslot = (int*)(ws + alloc((size_t)NIMG * SLOTCAP * 4));
    int* cm = (int*)(ws + alloc((size_t)NIMG * 5 * 4));
    unsigned long long* maskT = (unsigned long long*)(ws + alloc((size_t)NIMG * MT_IMG * 8));
    unsigned long long* keepWords = (unsigned long long*)(ws + alloc((size_t)NIMG * 5 * 16 * 8));

    hist_kernel<<<dim3(NIMG * BPI), dim3(1024), 0, stream>>>(obj, ghist);
    gather_kernel<<<dim3(NIMG * BPI), dim3(1024), 0, stream>>>(obj, ghist, gcand, gcnt,
                                                               gbstar);
    rankdecode_kernel<<<dim3(NIMG * 5), dim3(1024), 0, stream>>>(
        deltas, anchors, gcand, gcnt, gbstar, sx1, sy1, sx2, sy2, sscore,
        cx1, cy1, cx2, cy2, car, ckey, cslot, cm);
    mask_kernel<<<dim3(17, NIMG * 5), dim3(512), 0, stream>>>(cx1, cy1, cx2, cy2, car, cm,
                                                              maskT);
    scan_kernel<<<dim3(NIMG * 5), dim3(256), 0, stream>>>(maskT, cm, keepWords);
    scanout_kernel<<<dim3(NIMG), dim3(1024), 0, stream>>>(
        sx1, sy1, sx2, sy2, sscore, ckey, cslot, keepWords, out);
}